// Round 10
// baseline (611.227 us; speedup 1.0000x reference)
//
#include <hip/hip_runtime.h>

#define HCDIM 292
#define NHEAD 4
#define CDIM 73
#define SLOTS 5
#define NPERM 320
#define BN_EPS 1e-5f
#define LOG2E 1.44269504f

using u16x8 = __attribute__((ext_vector_type(8))) unsigned short;
using f32x4 = __attribute__((ext_vector_type(4))) float;   // MFMA acc
using u16x4 = __attribute__((ext_vector_type(4))) unsigned short;
using hf2   = __attribute__((ext_vector_type(2))) _Float16;  // arithmetic type
using v2h   = __attribute__((ext_vector_type(2))) __fp16;    // builtin boundary
using v8h   = __attribute__((ext_vector_type(8))) __fp16;    // MFMA frag

__device__ inline v2h pkrtz(float a, float b) {              // 2xf32 -> packed f16
  return __builtin_amdgcn_cvt_pkrtz(a, b);
}
__device__ inline float fdot2(hf2 a, hf2 b, float c) {
  return __builtin_amdgcn_fdot2(__builtin_bit_cast(v2h, a),
                                __builtin_bit_cast(v2h, b), c, false);
}
__device__ inline ushort f2h(float f) {
  _Float16 h = (_Float16)f;
  return __builtin_bit_cast(ushort, h);
}
__device__ inline float h2f(ushort v) {
  return (float)__builtin_bit_cast(_Float16, v);
}
__device__ inline hf2 habs2(hf2 a) {
  unsigned u = __builtin_bit_cast(unsigned, a) & 0x7fff7fffu;
  return __builtin_bit_cast(hf2, u);
}
// single-instruction exp2 (input pre-clamped; HW flushes large-negative to 0)
__device__ inline float fexp2(float x) {
  float r;
  asm("v_exp_f32 %0, %1" : "=v"(r) : "v"(x));
  return r;
}

// ACC += f32(lo/hi f16 of U) * W  -- v_fma_mix fuses the f16->f32 convert (exact)
#define FMAMIX_LO(ACC, W, U)                                                  \
  asm("v_fma_mix_f32 %0, %1, %2, %0 op_sel_hi:[1,0,0]"                        \
      : "+v"(ACC) : "v"(U), "v"(W))
#define FMAMIX_HI(ACC, W, U)                                                  \
  asm("v_fma_mix_f32 %0, %1, %2, %0 op_sel:[1,0,0] op_sel_hi:[1,0,0]"         \
      : "+v"(ACC) : "v"(U), "v"(W))

// all-lanes sum within each 16-lane row, VALU-pipe only (DPP)
__device__ inline float dpp16_allsum(float v) {
  union { float f; int i; } a, b;
  a.f = v;
  b.i = __builtin_amdgcn_update_dpp(0, a.i, 0xB1, 0xf, 0xf, true);
  a.f += b.f;
  b.i = __builtin_amdgcn_update_dpp(0, a.i, 0x4E, 0xf, 0xf, true);
  a.f += b.f;
  b.i = __builtin_amdgcn_update_dpp(0, a.i, 0x124, 0xf, 0xf, true);
  a.f += b.f;
  b.i = __builtin_amdgcn_update_dpp(0, a.i, 0x128, 0xf, 0xf, true);
  a.f += b.f;
  return a.f;
}

// permuted slot p -> original feature index (h*73+c); valid=false for 28 dead slots
__device__ inline int perm2feat(int p, bool& valid) {
  int h, c;
  if (p < 256) {
    h = p >> 6;
    c = ((p & 3) << 4) | ((p >> 2) & 15);
    valid = true;
  } else {
    int q = p - 256;
    h = q >> 4;
    c = 64 + (q & 15);
    valid = (q & 15) < (CDIM - 64);
  }
  return h * CDIM + c;
}

// ======================= mega prep: wperm L1+L2, vecperm, hist (1 dispatch) =========
__global__ __launch_bounds__(320) void k_prep(
    const float* __restrict__ Wl1, const float* __restrict__ bl1,
    const float* __restrict__ Wr1, const float* __restrict__ br1,
    const float* __restrict__ Wl2, const float* __restrict__ bl2,
    const float* __restrict__ Wr2, const float* __restrict__ br2,
    ushort* __restrict__ wb1, float* __restrict__ pb1,
    ushort* __restrict__ wb2, float* __restrict__ pb2,
    const float* __restrict__ att1, const float* __restrict__ b1v,
    const float* __restrict__ att2, const float* __restrict__ b2v,
    const float* __restrict__ gamma, const float* __restrict__ beta,
    const float* __restrict__ Wc, float* __restrict__ vecp,
    const int* __restrict__ dst, int* __restrict__ deg, int E) {
  int bx = blockIdx.x, t = threadIdx.x;
  if (bx >= 5 * NPERM) {                       // histogram part
    int i = (bx - 5 * NPERM) * 320 + t;
    int i4 = i * 4;
    if (i4 + 3 < E) {
      int4 d = *(const int4*)(dst + i4);
      atomicAdd(&deg[d.x], 1);
      atomicAdd(&deg[d.y], 1);
      atomicAdd(&deg[d.z], 1);
      atomicAdd(&deg[d.w], 1);
    } else {
      for (int k = i4; k < E; ++k) atomicAdd(&deg[dst[k]], 1);
    }
    return;
  }
  int seg = bx / NPERM;
  int p = bx - seg * NPERM;
  bool pv;
  int gn = perm2feat(p, pv);
  if (seg == 4) {                              // vecperm
    if (t < 8) {
      const float* src;
      switch (t) {
        case 0: src = att1; break;
        case 1: src = b1v; break;
        case 2: src = att2; break;
        case 3: src = b2v; break;
        case 4: src = gamma; break;
        case 5: src = beta; break;
        case 6: src = Wc; break;
        default: src = Wc + HCDIM; break;
      }
      vecp[t * NPERM + p] = pv ? src[gn] : 0.f;
    }
    return;
  }
  const float* W;
  const float* b;
  ushort* Wp;
  float* pb;
  int Kin, Kpad, kperm;
  if (seg < 2) {
    Kin = 128; Kpad = 128; kperm = 0;
    W = seg ? Wr1 : Wl1; b = seg ? br1 : bl1;
    Wp = wb1 + (size_t)seg * NPERM * 128; pb = pb1 + seg * NPERM;
  } else {
    Kin = HCDIM; Kpad = NPERM; kperm = 1;
    int s2 = seg - 2;
    W = s2 ? Wr2 : Wl2; b = s2 ? br2 : bl2;
    Wp = wb2 + (size_t)s2 * NPERM * NPERM; pb = pb2 + s2 * NPERM;
  }
  if (t < Kpad) {
    int gk = t;
    bool kv = t < Kin;
    if (kperm) { bool v2; gk = perm2feat(t, v2); kv = v2; }
    ushort v = 0;
    if (pv && kv) v = f2h(W[(size_t)gn * Kin + gk]);
    Wp[(size_t)p * Kpad + t] = v;
  }
  if (t == 0) pb[p] = pv ? b[gn] : 0.f;
}

// ======================= single-pass scan (decoupled lookback, unsigned states) =====
__global__ __launch_bounds__(256) void k_scan_lb(const int* __restrict__ deg,
                                                 unsigned* __restrict__ st,
                                                 int* __restrict__ row_ptr,
                                                 int* __restrict__ cursor,
                                                 int n, int E) {
  __shared__ int s[256];
  __shared__ int sprefix;
  int bid = blockIdx.x, t = threadIdx.x;
  int i = bid * 256 + t;
  int v = (i < n) ? deg[i] : 0;
  s[t] = v;
  __syncthreads();
  for (int off = 1; off < 256; off <<= 1) {
    int tv = (t >= off) ? s[t - off] : 0;
    __syncthreads();
    s[t] += tv;
    __syncthreads();
  }
  if (t == 0) {
    unsigned total = (unsigned)s[255];
    __hip_atomic_store(&st[bid], (1u << 30) | total, __ATOMIC_RELEASE,
                       __HIP_MEMORY_SCOPE_AGENT);
    unsigned run = 0;
    int p = bid - 1;
    while (p >= 0) {
      unsigned x;
      do {
        x = __hip_atomic_load(&st[p], __ATOMIC_ACQUIRE, __HIP_MEMORY_SCOPE_AGENT);
        if (x == 0u) __builtin_amdgcn_s_sleep(1);
      } while (x == 0u);
      run += x & 0x3FFFFFFFu;
      if ((x >> 30) == 2u) break;
      --p;
    }
    __hip_atomic_store(&st[bid], (2u << 30) | (run + total), __ATOMIC_RELEASE,
                       __HIP_MEMORY_SCOPE_AGENT);
    sprefix = (int)run;
  }
  __syncthreads();
  int run = sprefix;
  if (i < n) {
    int rp = run + s[t] - v;
    row_ptr[i] = rp;
    cursor[i] = rp;
  }
  if (i == 0) row_ptr[n] = E;
}

// ======================= A-in-LDS GEMM (+ optional csr_fill blocks) ==============
// ROWS=32 tile: MODE-1 LDS 44.5->23.5KB lifts occupancy 12->20 waves/CU (was the
// latency-bound bottleneck: MfmaUtil 9%, all pipes idle). B-columns double-buffered
// in registers (static indices after full unroll) so L2 latency hides under MFMAs.
template <int KS, int MODE, int FILL, int ROWS>
__global__ __launch_bounds__(256, 4) void k_gemm_a_lds(
    const void* __restrict__ Av, const ushort* __restrict__ Wb,
    const float* __restrict__ pb, const float* __restrict__ bnsum,
    const float* __restrict__ bnsq, const float* __restrict__ gp,
    const float* __restrict__ btp, float invN, ushort* __restrict__ o0,
    ushort* __restrict__ o1, int M,
    const int* __restrict__ srcs, const int* __restrict__ dsts,
    int* __restrict__ cursor, int* __restrict__ csr_src, int E, int gemmb) {
  if (FILL && (int)blockIdx.x >= gemmb) {
    int i = ((int)blockIdx.x - gemmb) * 256 + (int)threadIdx.x;
    int i4 = i * 4;
    if (i4 + 3 < E) {
      int4 s = *(const int4*)(srcs + i4);
      int4 d = *(const int4*)(dsts + i4);
      csr_src[atomicAdd(&cursor[d.x], 1)] = s.x;
      csr_src[atomicAdd(&cursor[d.y], 1)] = s.y;
      csr_src[atomicAdd(&cursor[d.z], 1)] = s.z;
      csr_src[atomicAdd(&cursor[d.w], 1)] = s.w;
    } else {
      for (int k = i4; k < E; ++k) {
        int pos = atomicAdd(&cursor[dsts[k]], 1);
        csr_src[pos] = srcs[k];
      }
    }
    return;
  }
  constexpr int KSTEPS = KS / 32;
  constexpr int STR = KS + 8;          // pad: rows 4 banks apart -> 2-way max (free)
  constexpr int MI = ROWS / 16;
  __shared__ ushort As[ROWS * STR];
  __shared__ float sScale[MODE ? NPERM : 1];
  __shared__ float sShift[MODE ? NPERM : 1];
  const int tid = threadIdx.x;
  const int rbase = blockIdx.x * ROWS;
  const int wave = tid >> 6, lane = tid & 63;
  const int quad = lane >> 4, lr = lane & 15;
  const int ct = wave;                 // 80-col slice within each 320-col half

  if constexpr (MODE == 0) {
    const float* X = (const float*)Av;
    constexpr int NIT = (ROWS * KS / 16) / 256;  // 16-float segments per thread
#pragma unroll
    for (int k = 0; k < NIT; ++k) {
      int idx = tid + k * 256;
      int row = idx >> 3, sg = idx & 7;          // KS=128 -> 8 segs/row
      int gr = rbase + row;
      if (gr >= M) gr = M - 1;
      const float4* p = (const float4*)(X + (size_t)gr * KS + sg * 16);
      float4 f0 = p[0], f1 = p[1], f2 = p[2], f3 = p[3];
      union { v2h h[4]; u16x8 v; } a, b;
      a.h[0] = pkrtz(f0.x, f0.y); a.h[1] = pkrtz(f0.z, f0.w);
      a.h[2] = pkrtz(f1.x, f1.y); a.h[3] = pkrtz(f1.z, f1.w);
      b.h[0] = pkrtz(f2.x, f2.y); b.h[1] = pkrtz(f2.z, f2.w);
      b.h[2] = pkrtz(f3.x, f3.y); b.h[3] = pkrtz(f3.z, f3.w);
      *(u16x8*)(As + row * STR + sg * 16) = a.v;
      *(u16x8*)(As + row * STR + sg * 16 + 8) = b.v;
    }
  } else {
    // BN coef (was k_bn_coef) computed once per block into LDS
    for (int c = tid; c < NPERM; c += 256) {
      float mu = bnsum[c] * invN;
      float var = bnsq[c] * invN - mu * mu;
      float sc = rsqrtf(var + BN_EPS) * gp[c];
      sScale[c] = sc;
      sShift[c] = btp[c] - mu * sc;
    }
    __syncthreads();
    const ushort* Hn = (const ushort*)Av;
    constexpr int NIT = (ROWS * KS / 8) / 256;   // 8-elem segments per thread
#pragma unroll
    for (int k = 0; k < NIT; ++k) {
      int idx = tid + k * 256;
      int row = idx / (KS / 8), c8 = idx - row * (KS / 8);
      int gr = rbase + row;
      if (gr >= M) gr = M - 1;
      u16x8 v = *(const u16x8*)(Hn + (size_t)gr * KS + c8 * 8);
      int c = c8 * 8;
      float4 s0 = *(const float4*)(sScale + c);
      float4 s1 = *(const float4*)(sScale + c + 4);
      float4 t0 = *(const float4*)(sShift + c);
      float4 t1 = *(const float4*)(sShift + c + 4);
      float f[8];
      f[0] = fmaf(h2f(v[0]), s0.x, t0.x);
      f[1] = fmaf(h2f(v[1]), s0.y, t0.y);
      f[2] = fmaf(h2f(v[2]), s0.z, t0.z);
      f[3] = fmaf(h2f(v[3]), s0.w, t0.w);
      f[4] = fmaf(h2f(v[4]), s1.x, t1.x);
      f[5] = fmaf(h2f(v[5]), s1.y, t1.y);
      f[6] = fmaf(h2f(v[6]), s1.z, t1.z);
      f[7] = fmaf(h2f(v[7]), s1.w, t1.w);
#pragma unroll
      for (int j = 0; j < 8; ++j) f[j] = (f[j] > 0.f) ? f[j] : 0.01f * f[j];
      union { v2h h4[4]; u16x8 o; } u;
#pragma unroll
      for (int j = 0; j < 4; ++j) u.h4[j] = pkrtz(f[2 * j], f[2 * j + 1]);
      *(u16x8*)(As + row * STR + c8 * 8) = u.o;
    }
  }
  __syncthreads();

  const ushort* arow[MI];
#pragma unroll
  for (int i = 0; i < MI; ++i) arow[i] = As + (i * 16 + lr) * STR;

#pragma unroll
  for (int y = 0; y < 2; ++y) {
    const ushort* bcol[5];
#pragma unroll
    for (int i = 0; i < 5; ++i)
      bcol[i] = Wb + (size_t)(y * 320 + ct * 80 + i * 16 + lr) * KS;

    f32x4 acc[MI][5] = {};
    v8h bfb[2][5];
#pragma unroll
    for (int i = 0; i < 5; ++i)
      bfb[0][i] = *(const v8h*)(bcol[i] + quad * 8);
#pragma unroll
    for (int s = 0; s < KSTEPS; ++s) {
      if (s + 1 < KSTEPS) {
#pragma unroll
        for (int i = 0; i < 5; ++i)
          bfb[(s + 1) & 1][i] = *(const v8h*)(bcol[i] + (s + 1) * 32 + quad * 8);
      }
      v8h af[MI];
#pragma unroll
      for (int i = 0; i < MI; ++i)
        af[i] = *(const v8h*)(arow[i] + s * 32 + quad * 8);
#pragma unroll
      for (int ni = 0; ni < 5; ++ni)
#pragma unroll
        for (int mi = 0; mi < MI; ++mi)
          acc[mi][ni] = __builtin_amdgcn_mfma_f32_16x16x32_f16(
              bfb[s & 1][ni], af[mi], acc[mi][ni], 0, 0, 0);
    }

    ushort* out = y ? o1 : o0;
    const int colbase = ct * 80;
    float4 pbv[5];
#pragma unroll
    for (int ni = 0; ni < 5; ++ni)
      pbv[ni] = *(const float4*)(pb + y * 320 + ct * 80 + ni * 16 + quad * 4);
#pragma unroll
    for (int mi = 0; mi < MI; ++mi) {
      int gm = rbase + mi * 16 + lr;
      if (gm >= M) continue;
      ushort* orow = out + (size_t)gm * NPERM + colbase + quad * 4;
#pragma unroll
      for (int ni = 0; ni < 5; ++ni) {
        union { v2h h[2]; u16x4 o; } u;
        u.h[0] = pkrtz(acc[mi][ni][0] + pbv[ni].x, acc[mi][ni][1] + pbv[ni].y);
        u.h[1] = pkrtz(acc[mi][ni][2] + pbv[ni].z, acc[mi][ni][3] + pbv[ni].w);
        *(u16x4*)(orow + ni * 16) = u.o;
      }
    }
  }
}

// ======================= fused GATv2 attention =======================
__global__ __launch_bounds__(128) void k_agg(const ushort* __restrict__ xl,
                                             const ushort* __restrict__ xr,
                                             const int* __restrict__ csr_src,
                                             const int* __restrict__ row_ptr,
                                             const float* __restrict__ attp,
                                             const float* __restrict__ bp,
                                             ushort* __restrict__ out, int n) {
  int wave = threadIdx.x >> 6, lane = threadIdx.x & 63;
  int d = blockIdx.x * 2 + wave;
  if (d >= n) return;
  int start = __builtin_amdgcn_readfirstlane(row_ptr[d]);
  int end = __builtin_amdgcn_readfirstlane(row_ptr[d + 1]);

  float4 bp4 = *(const float4*)(bp + lane * 4);
  float bp5 = bp[256 + lane];

  if (start >= end) {                      // isolated node -> bias only
    union { v2h h[2]; u16x4 o; } u;
    u.h[0] = pkrtz(bp4.x, bp4.y);
    u.h[1] = pkrtz(bp4.z, bp4.w);
    *(u16x4*)(out + (size_t)d * NPERM + lane * 4) = u.o;
    out[(size_t)d * NPERM + 256 + lane] = f2h(bp5);
    return;
  }

  const float C = 0.4f * LOG2E;
  float4 at4 = *(const float4*)(attp + lane * 4);
  hf2 av01{(_Float16)(C * at4.x), (_Float16)(C * at4.y)};
  hf2 av23{(_Float16)(C * at4.z), (_Float16)(C * at4.w)};
  hf2 av5{(_Float16)(C * attp[256 + lane]), (_Float16)0.f};

  hf2 xr01, xr23, xr5;
  {
    uint2 rr = *(const uint2*)(xr + (size_t)d * NPERM + lane * 4);
    xr01 = __builtin_bit_cast(hf2, rr.x);
    xr23 = __builtin_bit_cast(hf2, rr.y);
    xr5 = hf2{__builtin_bit_cast(_Float16, xr[(size_t)d * NPERM + 256 + lane]),
              (_Float16)0.f};
  }
  float Tb = fdot2(xr01, av01, fdot2(xr23, av23, fdot2(xr5, av5, 0.f)));
  Tb = dpp16_allsum(Tb);
  float prv = 1.5f * Tb;
  float acc[SLOTS] = {};
  float den = 0.f;
  int dg = end - start;
  int nfull = dg >> 2;
  int rem = dg & 3;

  uint2 s8[4];
  ushort s1[4];
#pragma unroll
  for (int k = 0; k < 4; ++k) {
    int e = start + k;
    if (e > end - 1) e = end - 1;
    int s = __builtin_amdgcn_readfirstlane(csr_src[e]);
    s8[k] = *(const uint2*)(xl + (size_t)s * NPERM + lane * 4);
    s1[k] = xl[(size_t)s * NPERM + 256 + lane];
  }

  for (int g = 0; g < nfull; ++g) {
    int ebase = start + g * 4 + 4;
    uint2 n8[4];
    ushort n1[4];
#pragma unroll
    for (int k = 0; k < 4; ++k) {
      int e = ebase + k;
      if (e > end - 1) e = end - 1;
      int s = __builtin_amdgcn_readfirstlane(csr_src[e]);
      n8[k] = *(const uint2*)(xl + (size_t)s * NPERM + lane * 4);
      n1[k] = xl[(size_t)s * NPERM + 256 + lane];
    }

    float z[4];
#pragma unroll
    for (int k = 0; k < 4; ++k) {
      hf2 x01 = __builtin_bit_cast(hf2, s8[k].x);
      hf2 x23 = __builtin_bit_cast(hf2, s8[k].y);
      hf2 x5{__builtin_bit_cast(_Float16, s1[k]), (_Float16)0.f};
      float T = fdot2(habs2(x01 + xr01), av01,
                fdot2(habs2(x23 + xr23), av23,
                fdot2(habs2(x5 + xr5), av5, 0.f)));
      float Tl = fdot2(x01, av01, fdot2(x23, av23, fdot2(x5, av5, 0.f)));
      z[k] = fmaf(1.5f, Tl, T);
    }
#pragma unroll
    for (int k = 0; k < 4; ++k) z[k] = dpp16_allsum(z[k]);
    float w[4];
#pragma unroll
    for (int k = 0; k < 4; ++k) {
      w[k] = fexp2(fminf(z[k] + prv, 80.f));
      den += w[k];
    }
#pragma unroll
    for (int k = 0; k < 4; ++k) {
      unsigned ux = s8[k].x, uy = s8[k].y, u5 = (unsigned)s1[k];
      FMAMIX_LO(acc[0], w[k], ux);
      FMAMIX_HI(acc[1], w[k], ux);
      FMAMIX_LO(acc[2], w[k], uy);
      FMAMIX_HI(acc[3], w[k], uy);
      FMAMIX_LO(acc[4], w[k], u5);
    }
#pragma unroll
    for (int k = 0; k < 4; ++k) { s8[k] = n8[k]; s1[k] = n1[k]; }
  }

#pragma unroll
  for (int k = 0; k < 3; ++k) {
    if (k < rem) {
      hf2 x01 = __builtin_bit_cast(hf2, s8[k].x);
      hf2 x23 = __builtin_bit_cast(hf2, s8[k].y);
      hf2 x5{__builtin_bit_cast(_Float16, s1[k]), (_Float16)0.f};
      float T = fdot2(habs2(x01 + xr01), av01,
                fdot2(habs2(x23 + xr23), av23,
                fdot2(habs2(x5 + xr5), av5, 0.f)));
      float Tl = fdot2(x01, av01, fdot2(x23, av23, fdot2(x5, av5, 0.f)));
      float z = fmaf(1.5f, Tl, T);
      z = dpp16_allsum(z);
      float w = fexp2(fminf(z + prv, 80.f));
      den += w;
      unsigned ux = s8[k].x, uy = s8[k].y, u5 = (unsigned)s1[k];
      FMAMIX_LO(acc[0], w, ux);
      FMAMIX_HI(acc[1], w, ux);
      FMAMIX_LO(acc[2], w, uy);
      FMAMIX_HI(acc[3], w, uy);
      FMAMIX_LO(acc[4], w, u5);
    }
  }

  float inv = 1.f / (den + 1e-16f);
  union { v2h h[2]; u16x4 o; } u;
  u.h[0] = pkrtz(fmaf(acc[0], inv, bp4.x), fmaf(acc[1], inv, bp4.y));
  u.h[1] = pkrtz(fmaf(acc[2], inv, bp4.z), fmaf(acc[3], inv, bp4.w));
  *(u16x4*)(out + (size_t)d * NPERM + lane * 4) = u.o;
  out[(size_t)d * NPERM + 256 + lane] = f2h(fmaf(acc[4], inv, bp5));
}

// ======================= BatchNorm reduce (pure atomicAdd; no fences) =============
__global__ __launch_bounds__(320) void k_bn_reduce(const ushort* __restrict__ h,
                                                   float* __restrict__ colsum,
                                                   float* __restrict__ colsq,
                                                   int n, int rows_per_block) {
  int c = threadIdx.x;
  int r0 = blockIdx.x * rows_per_block;
  int r1 = min(r0 + rows_per_block, n);
  float s = 0.f, s2 = 0.f;
  for (int r = r0; r < r1; ++r) {
    float v = h2f(h[(size_t)r * NPERM + c]);
    s += v;
    s2 += v * v;
  }
  atomicAdd(&colsum[c], s);
  atomicAdd(&colsq[c], s2);
}

// ======================= fused BN(coef inline) + leaky-relu + classifier ===========
__global__ __launch_bounds__(256) void k_bn_classifier(
    const ushort* __restrict__ h, const float* __restrict__ bnsum,
    const float* __restrict__ bnsq, const float* __restrict__ gp,
    const float* __restrict__ btp, float invN, const float* __restrict__ wc0,
    const float* __restrict__ wc1, const float* __restrict__ bc,
    float* __restrict__ out, int n) {
  int wave = threadIdx.x >> 6, lane = threadIdx.x & 63;
  int r = blockIdx.x * 4 + wave;
  if (r >= n) return;
  float a0 = 0.f, a1 = 0.f;
#pragma unroll
  for (int k = 0; k < SLOTS; ++k) {
    int slot = lane + 64 * k;
    float mu = bnsum[slot] * invN;
    float var = bnsq[slot] * invN - mu * mu;
    float sc = rsqrtf(var + BN_EPS) * gp[slot];
    float sh = btp[slot] - mu * sc;
    float v = fmaf(h2f(h[(size_t)r * NPERM + slot]), sc, sh);
    v = (v > 0.f) ? v : 0.01f * v;
    a0 = fmaf(v, wc0[slot], a0);
    a1 = fmaf(v, wc1[slot], a1);
  }
#pragma unroll
  for (int off = 32; off > 0; off >>= 1) {
    a0 += __shfl_xor(a0, off, 64);
    a1 += __shfl_xor(a1, off, 64);
  }
  if (lane == 0) {
    out[(size_t)2 * r] = a0 + bc[0];
    out[(size_t)2 * r + 1] = a1 + bc[1];
  }
}

// ======================= host launch =======================
extern "C" void kernel_launch(void* const* d_in, const int* in_sizes, int n_in,
                              void* d_out, int out_size, void* d_ws, size_t ws_size,
                              hipStream_t stream) {
  const float* x      = (const float*)d_in[0];
  const int*   eidx   = (const int*)d_in[1];
  const float* Wl1    = (const float*)d_in[2];
  const float* bl1    = (const float*)d_in[3];
  const float* Wr1    = (const float*)d_in[4];
  const float* br1    = (const float*)d_in[5];
  const float* att1   = (const float*)d_in[6];
  const float* b1     = (const float*)d_in[7];
  const float* Wl2    = (const float*)d_in[8];
  const float* bl2    = (const float*)d_in[9];
  const float* Wr2    = (const float*)d_in[10];
  const float* br2    = (const float*)d_in[11];
  const float* att2   = (const float*)d_in[12];
  const float* b2     = (const float*)d_in[13];
  const float* gamma  = (const float*)d_in[14];
  const float* beta   = (const float*)d_in[15];
  const float* Wc     = (const float*)d_in[16];
  const float* bc     = (const float*)d_in[17];
  float* out = (float*)d_out;

  const int FIN = 128;
  const int N = in_sizes[0] / FIN;   // 50000
  const int E = in_sizes[1] / 2;     // 800000

  const int* src = eidx;
  const int* dst = eidx + E;

  // ---- workspace layout ----
  ushort* h      = (ushort*)d_ws;                 // N*320 f16 permuted
  ushort* xl     = h + (size_t)N * NPERM;         // N*320
  ushort* xr     = xl + (size_t)N * NPERM;        // N*320
  ushort* wb1    = xr + (size_t)N * NPERM;        // 640*128 (L1 weights)
  ushort* wb2    = wb1 + (size_t)2 * NPERM * 128; // 640*320 (L2 weights)
  float* pb1     = (float*)(wb2 + (size_t)2 * NPERM * NPERM);  // 640
  float* pb2     = pb1 + 2 * NPERM;               // 640
  float* vecp    = pb2 + 2 * NPERM;               // 8*320
  int* row_ptr   = (int*)(vecp + 8 * NPERM);      // N+1
  int* cursor    = row_ptr + N + 1;               // N
  int* csr_src   = cursor + N;                    // E
  // ---- contiguous zero-init region (ONE memset) ----
  int* deg       = csr_src + E;                   // N
  unsigned* scanst = (unsigned*)(deg + N);        // 256 (lookback states)
  int* tickets   = (int*)(scanst + 256);          // 4 (unused; layout kept)
  float* colsum1 = (float*)(tickets + 4);         // 320
  float* colsq1  = colsum1 + NPERM;               // 320
  float* colsum2 = colsq1 + NPERM;                // 320
  float* colsq2  = colsum2 + NPERM;               // 320
  const size_t zero_bytes = (size_t)(N + 256 + 4 + 4 * NPERM) * 4;

  const int G = (N + 255) / 256;                  // scan blocks (196 < 256 CUs)
  const int AGGB = (N + 3) / 4;
  const int AGG2 = (N + 1) / 2;
  const int GEMMB = (N + 31) / 32;                // 32-row tiles
  const int FB = (E + 1023) / 1024;               // fill blocks (256 thr x 4 edges)
  const int HISTB = (E + 1279) / 1280;            // hist blocks (320 thr x 4 edges)

  const float* att1p = vecp;
  const float* b1p   = vecp + NPERM;
  const float* att2p = vecp + 2 * NPERM;
  const float* b2p   = vecp + 3 * NPERM;
  const float* gp    = vecp + 4 * NPERM;
  const float* btp   = vecp + 5 * NPERM;
  const float* wc0   = vecp + 6 * NPERM;
  const float* wc1   = vecp + 7 * NPERM;

  const int BNB = 1024;
  const int RPB = (N + BNB - 1) / BNB;
  const float invN = 1.f / (float)N;

  // 1: all zero-init in one memset
  hipMemsetAsync(deg, 0, zero_bytes, stream);
  // 2: weights L1+L2 + vecperm + histogram
  k_prep<<<5 * NPERM + HISTB, 320, 0, stream>>>(
      Wl1, bl1, Wr1, br1, Wl2, bl2, Wr2, br2, wb1, pb1, wb2, pb2,
      att1, b1, att2, b2, gamma, beta, Wc, vecp, dst, deg, E);
  // 3: single-pass scan -> row_ptr, cursor
  k_scan_lb<<<G, 256, 0, stream>>>(deg, scanst, row_ptr, cursor, N, E);
  // 4: GEMM layer1 + csr_fill (merged dispatch, independent work)
  k_gemm_a_lds<128, 0, 1, 32><<<GEMMB + FB, 256, 0, stream>>>(
      (const void*)x, wb1, pb1, nullptr, nullptr, nullptr, nullptr, 0.f,
      xl, xr, N, src, dst, cursor, csr_src, E, GEMMB);
  // 5: attention layer1
  k_agg<<<AGG2, 128, 0, stream>>>(xl, xr, csr_src, row_ptr, att1p, b1p, h, N);
  // 6: BN reduce layer1 (coef computed by consumer)
  k_bn_reduce<<<BNB, NPERM, 0, stream>>>(h, colsum1, colsq1, N, RPB);
  // 7: GEMM layer2 (BN coef + BN+leaky fused into A staging)
  k_gemm_a_lds<NPERM, 1, 0, 32><<<GEMMB, 256, 0, stream>>>(
      (const void*)h, wb2, pb2, colsum1, colsq1, gp, btp, invN,
      xl, xr, N, nullptr, nullptr, nullptr, nullptr, 0, GEMMB);
  // 8: attention layer2
  k_agg<<<AGG2, 128, 0, stream>>>(xl, xr, csr_src, row_ptr, att2p, b2p, h, N);
  // 9: BN reduce layer2
  k_bn_reduce<<<BNB, NPERM, 0, stream>>>(h, colsum2, colsq2, N, RPB);
  // 10: classifier (BN coef inline)
  k_bn_classifier<<<AGGB, 256, 0, stream>>>(h, colsum2, colsq2, gp, btp, invN,
                                            wc0, wc1, bc, out, N);
}

// Round 11
// 536.546 us; speedup vs baseline: 1.1392x; 1.1392x over previous
//
#include <hip/hip_runtime.h>

#define HCDIM 292
#define NHEAD 4
#define CDIM 73
#define SLOTS 5
#define NPERM 320
#define BN_EPS 1e-5f
#define LOG2E 1.44269504f

using u16x8 = __attribute__((ext_vector_type(8))) unsigned short;
using f32x4 = __attribute__((ext_vector_type(4))) float;   // MFMA acc
using u16x4 = __attribute__((ext_vector_type(4))) unsigned short;
using hf2   = __attribute__((ext_vector_type(2))) _Float16;  // arithmetic type
using v2h   = __attribute__((ext_vector_type(2))) __fp16;    // builtin boundary
using v8h   = __attribute__((ext_vector_type(8))) __fp16;    // MFMA frag

__device__ inline v2h pkrtz(float a, float b) {              // 2xf32 -> packed f16
  return __builtin_amdgcn_cvt_pkrtz(a, b);
}
__device__ inline float fdot2(hf2 a, hf2 b, float c) {
  return __builtin_amdgcn_fdot2(__builtin_bit_cast(v2h, a),
                                __builtin_bit_cast(v2h, b), c, false);
}
__device__ inline ushort f2h(float f) {
  _Float16 h = (_Float16)f;
  return __builtin_bit_cast(ushort, h);
}
__device__ inline float h2f(ushort v) {
  return (float)__builtin_bit_cast(_Float16, v);
}
__device__ inline hf2 habs2(hf2 a) {
  unsigned u = __builtin_bit_cast(unsigned, a) & 0x7fff7fffu;
  return __builtin_bit_cast(hf2, u);
}
// single-instruction exp2 (input pre-clamped; HW flushes large-negative to 0)
__device__ inline float fexp2(float x) {
  float r;
  asm("v_exp_f32 %0, %1" : "=v"(r) : "v"(x));
  return r;
}

// ACC += f32(lo/hi f16 of U) * W  -- v_fma_mix fuses the f16->f32 convert (exact)
#define FMAMIX_LO(ACC, W, U)                                                  \
  asm("v_fma_mix_f32 %0, %1, %2, %0 op_sel_hi:[1,0,0]"                        \
      : "+v"(ACC) : "v"(U), "v"(W))
#define FMAMIX_HI(ACC, W, U)                                                  \
  asm("v_fma_mix_f32 %0, %1, %2, %0 op_sel:[1,0,0] op_sel_hi:[1,0,0]"         \
      : "+v"(ACC) : "v"(U), "v"(W))

// all-lanes sum within each 16-lane row, VALU-pipe only (DPP)
__device__ inline float dpp16_allsum(float v) {
  union { float f; int i; } a, b;
  a.f = v;
  b.i = __builtin_amdgcn_update_dpp(0, a.i, 0xB1, 0xf, 0xf, true);
  a.f += b.f;
  b.i = __builtin_amdgcn_update_dpp(0, a.i, 0x4E, 0xf, 0xf, true);
  a.f += b.f;
  b.i = __builtin_amdgcn_update_dpp(0, a.i, 0x124, 0xf, 0xf, true);
  a.f += b.f;
  b.i = __builtin_amdgcn_update_dpp(0, a.i, 0x128, 0xf, 0xf, true);
  a.f += b.f;
  return a.f;
}

// permuted slot p -> original feature index (h*73+c); valid=false for 28 dead slots
__device__ inline int perm2feat(int p, bool& valid) {
  int h, c;
  if (p < 256) {
    h = p >> 6;
    c = ((p & 3) << 4) | ((p >> 2) & 15);
    valid = true;
  } else {
    int q = p - 256;
    h = q >> 4;
    c = 64 + (q & 15);
    valid = (q & 15) < (CDIM - 64);
  }
  return h * CDIM + c;
}

// ======================= mega prep: wperm L1+L2, vecperm, hist (1 dispatch) =========
__global__ __launch_bounds__(320) void k_prep(
    const float* __restrict__ Wl1, const float* __restrict__ bl1,
    const float* __restrict__ Wr1, const float* __restrict__ br1,
    const float* __restrict__ Wl2, const float* __restrict__ bl2,
    const float* __restrict__ Wr2, const float* __restrict__ br2,
    ushort* __restrict__ wb1, float* __restrict__ pb1,
    ushort* __restrict__ wb2, float* __restrict__ pb2,
    const float* __restrict__ att1, const float* __restrict__ b1v,
    const float* __restrict__ att2, const float* __restrict__ b2v,
    const float* __restrict__ gamma, const float* __restrict__ beta,
    const float* __restrict__ Wc, float* __restrict__ vecp,
    const int* __restrict__ dst, int* __restrict__ deg, int E) {
  int bx = blockIdx.x, t = threadIdx.x;
  if (bx >= 5 * NPERM) {                       // histogram part
    int i = (bx - 5 * NPERM) * 320 + t;
    int i4 = i * 4;
    if (i4 + 3 < E) {
      int4 d = *(const int4*)(dst + i4);
      atomicAdd(&deg[d.x], 1);
      atomicAdd(&deg[d.y], 1);
      atomicAdd(&deg[d.z], 1);
      atomicAdd(&deg[d.w], 1);
    } else {
      for (int k = i4; k < E; ++k) atomicAdd(&deg[dst[k]], 1);
    }
    return;
  }
  int seg = bx / NPERM;
  int p = bx - seg * NPERM;
  bool pv;
  int gn = perm2feat(p, pv);
  if (seg == 4) {                              // vecperm
    if (t < 8) {
      const float* src;
      switch (t) {
        case 0: src = att1; break;
        case 1: src = b1v; break;
        case 2: src = att2; break;
        case 3: src = b2v; break;
        case 4: src = gamma; break;
        case 5: src = beta; break;
        case 6: src = Wc; break;
        default: src = Wc + HCDIM; break;
      }
      vecp[t * NPERM + p] = pv ? src[gn] : 0.f;
    }
    return;
  }
  const float* W;
  const float* b;
  ushort* Wp;
  float* pb;
  int Kin, Kpad, kperm;
  if (seg < 2) {
    Kin = 128; Kpad = 128; kperm = 0;
    W = seg ? Wr1 : Wl1; b = seg ? br1 : bl1;
    Wp = wb1 + (size_t)seg * NPERM * 128; pb = pb1 + seg * NPERM;
  } else {
    Kin = HCDIM; Kpad = NPERM; kperm = 1;
    int s2 = seg - 2;
    W = s2 ? Wr2 : Wl2; b = s2 ? br2 : bl2;
    Wp = wb2 + (size_t)s2 * NPERM * NPERM; pb = pb2 + s2 * NPERM;
  }
  if (t < Kpad) {
    int gk = t;
    bool kv = t < Kin;
    if (kperm) { bool v2; gk = perm2feat(t, v2); kv = v2; }
    ushort v = 0;
    if (pv && kv) v = f2h(W[(size_t)gn * Kin + gk]);
    Wp[(size_t)p * Kpad + t] = v;
  }
  if (t == 0) pb[p] = pv ? b[gn] : 0.f;
}

// ======================= single-pass scan (WAVE-PARALLEL lookback) =======================
// Old lookback walked 1 predecessor per L2 round-trip (worst ~196 serial steps).
// Now 64 lanes read 64 predecessor states per trip -> <=4 iterations.
__global__ __launch_bounds__(256) void k_scan_lb(const int* __restrict__ deg,
                                                 unsigned* __restrict__ st,
                                                 int* __restrict__ row_ptr,
                                                 int* __restrict__ cursor,
                                                 int n, int E) {
  __shared__ int s[256];
  __shared__ int sprefix;
  int bid = blockIdx.x, t = threadIdx.x;
  int i = bid * 256 + t;
  int v = (i < n) ? deg[i] : 0;
  s[t] = v;
  __syncthreads();
  for (int off = 1; off < 256; off <<= 1) {
    int tv = (t >= off) ? s[t - off] : 0;
    __syncthreads();
    s[t] += tv;
    __syncthreads();
  }
  unsigned total = (unsigned)s[255];
  if (t == 0)
    __hip_atomic_store(&st[bid], (1u << 30) | total, __ATOMIC_RELEASE,
                       __HIP_MEMORY_SCOPE_AGENT);
  if (t < 64) {
    unsigned run = 0;
    int base = bid - 1;
    bool done = (bid == 0);
    while (!done) {
      int p = base - t;                 // lane t looks at predecessor base-t
      unsigned myv = 0;
      int stat = 2;                     // p<0 acts as inclusive-0 terminator
      if (p >= 0) {
        unsigned x;
        do {
          x = __hip_atomic_load(&st[p], __ATOMIC_ACQUIRE,
                                __HIP_MEMORY_SCOPE_AGENT);
          if (x == 0u) __builtin_amdgcn_s_sleep(1);
        } while (x == 0u);
        myv = x & 0x3FFFFFFFu;
        stat = (int)(x >> 30);
      }
      unsigned long long m = __ballot(stat == 2);
      unsigned contrib;
      if (m) {
        int fi = __ffsll((long long)m) - 1;   // nearest inclusive predecessor
        contrib = (t <= fi) ? myv : 0u;
        done = true;
      } else {
        contrib = myv;                  // all 64 are aggregates; step back
        base -= 64;
      }
#pragma unroll
      for (int off = 32; off > 0; off >>= 1)
        contrib += (unsigned)__shfl_xor((int)contrib, off, 64);
      run += contrib;
    }
    if (t == 0) {
      __hip_atomic_store(&st[bid], (2u << 30) | (run + total), __ATOMIC_RELEASE,
                         __HIP_MEMORY_SCOPE_AGENT);
      sprefix = (int)run;
    }
  }
  __syncthreads();
  int run = sprefix;
  if (i < n) {
    int rp = run + s[t] - v;
    row_ptr[i] = rp;
    cursor[i] = rp;
  }
  if (i == 0) row_ptr[n] = E;
}

// ======================= A-in-LDS GEMM (+ optional csr_fill blocks) ==============
// ROWS=64 (round-9's 32-row tile doubled per-block B traffic: reverted).
// launch_bounds(256,3): VGPR cap 170 so acc(80)+bfb(40)+af(16) can LIVE in regs --
// at (256,4)'s 128 cap the allocator sank the B prefetch (VGPR=64/100 observed),
// exposing full L2 latency per K-step. sched_barrier(0x7) pins prefetch issue.
template <int KS, int MODE, int FILL, int ROWS>
__global__ __launch_bounds__(256, 3) void k_gemm_a_lds(
    const void* __restrict__ Av, const ushort* __restrict__ Wb,
    const float* __restrict__ pb, const float* __restrict__ bnsum,
    const float* __restrict__ bnsq, const float* __restrict__ gp,
    const float* __restrict__ btp, float invN, ushort* __restrict__ o0,
    ushort* __restrict__ o1, int M,
    const int* __restrict__ srcs, const int* __restrict__ dsts,
    int* __restrict__ cursor, int* __restrict__ csr_src, int E, int gemmb) {
  if (FILL && (int)blockIdx.x >= gemmb) {
    int i = ((int)blockIdx.x - gemmb) * 256 + (int)threadIdx.x;
    int i4 = i * 4;
    if (i4 + 3 < E) {
      int4 s = *(const int4*)(srcs + i4);
      int4 d = *(const int4*)(dsts + i4);
      csr_src[atomicAdd(&cursor[d.x], 1)] = s.x;
      csr_src[atomicAdd(&cursor[d.y], 1)] = s.y;
      csr_src[atomicAdd(&cursor[d.z], 1)] = s.z;
      csr_src[atomicAdd(&cursor[d.w], 1)] = s.w;
    } else {
      for (int k = i4; k < E; ++k) {
        int pos = atomicAdd(&cursor[dsts[k]], 1);
        csr_src[pos] = srcs[k];
      }
    }
    return;
  }
  constexpr int KSTEPS = KS / 32;
  constexpr int STR = KS + 8;          // pad: rows 4 banks apart
  constexpr int MI = ROWS / 16;
  __shared__ ushort As[ROWS * STR];
  __shared__ float sScale[MODE ? NPERM : 1];
  __shared__ float sShift[MODE ? NPERM : 1];
  const int tid = threadIdx.x;
  const int rbase = blockIdx.x * ROWS;
  const int wave = tid >> 6, lane = tid & 63;
  const int quad = lane >> 4, lr = lane & 15;
  const int ct = wave;                 // 80-col slice within each 320-col half

  if constexpr (MODE == 0) {
    const float* X = (const float*)Av;
    constexpr int NIT = (ROWS * KS / 16) / 256;  // 16-float segments per thread
#pragma unroll
    for (int k = 0; k < NIT; ++k) {
      int idx = tid + k * 256;
      int row = idx >> 3, sg = idx & 7;          // KS=128 -> 8 segs/row
      int gr = rbase + row;
      if (gr >= M) gr = M - 1;
      const float4* p = (const float4*)(X + (size_t)gr * KS + sg * 16);
      float4 f0 = p[0], f1 = p[1], f2 = p[2], f3 = p[3];
      union { v2h h[4]; u16x8 v; } a, b;
      a.h[0] = pkrtz(f0.x, f0.y); a.h[1] = pkrtz(f0.z, f0.w);
      a.h[2] = pkrtz(f1.x, f1.y); a.h[3] = pkrtz(f1.z, f1.w);
      b.h[0] = pkrtz(f2.x, f2.y); b.h[1] = pkrtz(f2.z, f2.w);
      b.h[2] = pkrtz(f3.x, f3.y); b.h[3] = pkrtz(f3.z, f3.w);
      *(u16x8*)(As + row * STR + sg * 16) = a.v;
      *(u16x8*)(As + row * STR + sg * 16 + 8) = b.v;
    }
  } else {
    // BN coef (was k_bn_coef) computed once per block into LDS
    for (int c = tid; c < NPERM; c += 256) {
      float mu = bnsum[c] * invN;
      float var = bnsq[c] * invN - mu * mu;
      float sc = rsqrtf(var + BN_EPS) * gp[c];
      sScale[c] = sc;
      sShift[c] = btp[c] - mu * sc;
    }
    __syncthreads();
    const ushort* Hn = (const ushort*)Av;
    constexpr int NIT = (ROWS * KS / 8) / 256;   // 8-elem segments per thread
#pragma unroll
    for (int k = 0; k < NIT; ++k) {
      int idx = tid + k * 256;
      int row = idx / (KS / 8), c8 = idx - row * (KS / 8);
      int gr = rbase + row;
      if (gr >= M) gr = M - 1;
      u16x8 v = *(const u16x8*)(Hn + (size_t)gr * KS + c8 * 8);
      int c = c8 * 8;
      float4 s0 = *(const float4*)(sScale + c);
      float4 s1 = *(const float4*)(sScale + c + 4);
      float4 t0 = *(const float4*)(sShift + c);
      float4 t1 = *(const float4*)(sShift + c + 4);
      float f[8];
      f[0] = fmaf(h2f(v[0]), s0.x, t0.x);
      f[1] = fmaf(h2f(v[1]), s0.y, t0.y);
      f[2] = fmaf(h2f(v[2]), s0.z, t0.z);
      f[3] = fmaf(h2f(v[3]), s0.w, t0.w);
      f[4] = fmaf(h2f(v[4]), s1.x, t1.x);
      f[5] = fmaf(h2f(v[5]), s1.y, t1.y);
      f[6] = fmaf(h2f(v[6]), s1.z, t1.z);
      f[7] = fmaf(h2f(v[7]), s1.w, t1.w);
#pragma unroll
      for (int j = 0; j < 8; ++j) f[j] = (f[j] > 0.f) ? f[j] : 0.01f * f[j];
      union { v2h h4[4]; u16x8 o; } u;
#pragma unroll
      for (int j = 0; j < 4; ++j) u.h4[j] = pkrtz(f[2 * j], f[2 * j + 1]);
      *(u16x8*)(As + row * STR + c8 * 8) = u.o;
    }
  }
  __syncthreads();

  const ushort* arow[MI];
#pragma unroll
  for (int i = 0; i < MI; ++i) arow[i] = As + (i * 16 + lr) * STR;

#pragma unroll
  for (int y = 0; y < 2; ++y) {
    const ushort* bcol[5];
#pragma unroll
    for (int i = 0; i < 5; ++i)
      bcol[i] = Wb + (size_t)(y * 320 + ct * 80 + i * 16 + lr) * KS;

    f32x4 acc[MI][5] = {};
    v8h bfb[2][5];
#pragma unroll
    for (int i = 0; i < 5; ++i)
      bfb[0][i] = *(const v8h*)(bcol[i] + quad * 8);
#pragma unroll
    for (int s = 0; s < KSTEPS; ++s) {
      if (s + 1 < KSTEPS) {
#pragma unroll
        for (int i = 0; i < 5; ++i)
          bfb[(s + 1) & 1][i] = *(const v8h*)(bcol[i] + (s + 1) * 32 + quad * 8);
      }
      v8h af[MI];
#pragma unroll
      for (int i = 0; i < MI; ++i)
        af[i] = *(const v8h*)(arow[i] + s * 32 + quad * 8);
      __builtin_amdgcn_sched_barrier(0x7);   // VMEM/DS/MFMA may not cross
#pragma unroll
      for (int ni = 0; ni < 5; ++ni)
#pragma unroll
        for (int mi = 0; mi < MI; ++mi)
          acc[mi][ni] = __builtin_amdgcn_mfma_f32_16x16x32_f16(
              bfb[s & 1][ni], af[mi], acc[mi][ni], 0, 0, 0);
    }

    ushort* out = y ? o1 : o0;
    const int colbase = ct * 80;
    float4 pbv[5];
#pragma unroll
    for (int ni = 0; ni < 5; ++ni)
      pbv[ni] = *(const float4*)(pb + y * 320 + ct * 80 + ni * 16 + quad * 4);
#pragma unroll
    for (int mi = 0; mi < MI; ++mi) {
      int gm = rbase + mi * 16 + lr;
      if (gm >= M) continue;
      ushort* orow = out + (size_t)gm * NPERM + colbase + quad * 4;
#pragma unroll
      for (int ni = 0; ni < 5; ++ni) {
        union { v2h h[2]; u16x4 o; } u;
        u.h[0] = pkrtz(acc[mi][ni][0] + pbv[ni].x, acc[mi][ni][1] + pbv[ni].y);
        u.h[1] = pkrtz(acc[mi][ni][2] + pbv[ni].z, acc[mi][ni][3] + pbv[ni].w);
        *(u16x4*)(orow + ni * 16) = u.o;
      }
    }
  }
}

// ======================= fused GATv2 attention =======================
__global__ __launch_bounds__(128) void k_agg(const ushort* __restrict__ xl,
                                             const ushort* __restrict__ xr,
                                             const int* __restrict__ csr_src,
                                             const int* __restrict__ row_ptr,
                                             const float* __restrict__ attp,
                                             const float* __restrict__ bp,
                                             ushort* __restrict__ out, int n) {
  int wave = threadIdx.x >> 6, lane = threadIdx.x & 63;
  int d = blockIdx.x * 2 + wave;
  if (d >= n) return;
  int start = __builtin_amdgcn_readfirstlane(row_ptr[d]);
  int end = __builtin_amdgcn_readfirstlane(row_ptr[d + 1]);

  float4 bp4 = *(const float4*)(bp + lane * 4);
  float bp5 = bp[256 + lane];

  if (start >= end) {                      // isolated node -> bias only
    union { v2h h[2]; u16x4 o; } u;
    u.h[0] = pkrtz(bp4.x, bp4.y);
    u.h[1] = pkrtz(bp4.z, bp4.w);
    *(u16x4*)(out + (size_t)d * NPERM + lane * 4) = u.o;
    out[(size_t)d * NPERM + 256 + lane] = f2h(bp5);
    return;
  }

  const float C = 0.4f * LOG2E;
  float4 at4 = *(const float4*)(attp + lane * 4);
  hf2 av01{(_Float16)(C * at4.x), (_Float16)(C * at4.y)};
  hf2 av23{(_Float16)(C * at4.z), (_Float16)(C * at4.w)};
  hf2 av5{(_Float16)(C * attp[256 + lane]), (_Float16)0.f};

  hf2 xr01, xr23, xr5;
  {
    uint2 rr = *(const uint2*)(xr + (size_t)d * NPERM + lane * 4);
    xr01 = __builtin_bit_cast(hf2, rr.x);
    xr23 = __builtin_bit_cast(hf2, rr.y);
    xr5 = hf2{__builtin_bit_cast(_Float16, xr[(size_t)d * NPERM + 256 + lane]),
              (_Float16)0.f};
  }
  float Tb = fdot2(xr01, av01, fdot2(xr23, av23, fdot2(xr5, av5, 0.f)));
  Tb = dpp16_allsum(Tb);
  float prv = 1.5f * Tb;
  float acc[SLOTS] = {};
  float den = 0.f;
  int dg = end - start;
  int nfull = dg >> 2;
  int rem = dg & 3;

  uint2 s8[4];
  ushort s1[4];
#pragma unroll
  for (int k = 0; k < 4; ++k) {
    int e = start + k;
    if (e > end - 1) e = end - 1;
    int s = __builtin_amdgcn_readfirstlane(csr_src[e]);
    s8[k] = *(const uint2*)(xl + (size_t)s * NPERM + lane * 4);
    s1[k] = xl[(size_t)s * NPERM + 256 + lane];
  }

  for (int g = 0; g < nfull; ++g) {
    int ebase = start + g * 4 + 4;
    uint2 n8[4];
    ushort n1[4];
#pragma unroll
    for (int k = 0; k < 4; ++k) {
      int e = ebase + k;
      if (e > end - 1) e = end - 1;
      int s = __builtin_amdgcn_readfirstlane(csr_src[e]);
      n8[k] = *(const uint2*)(xl + (size_t)s * NPERM + lane * 4);
      n1[k] = xl[(size_t)s * NPERM + 256 + lane];
    }

    float z[4];
#pragma unroll
    for (int k = 0; k < 4; ++k) {
      hf2 x01 = __builtin_bit_cast(hf2, s8[k].x);
      hf2 x23 = __builtin_bit_cast(hf2, s8[k].y);
      hf2 x5{__builtin_bit_cast(_Float16, s1[k]), (_Float16)0.f};
      float T = fdot2(habs2(x01 + xr01), av01,
                fdot2(habs2(x23 + xr23), av23,
                fdot2(habs2(x5 + xr5), av5, 0.f)));
      float Tl = fdot2(x01, av01, fdot2(x23, av23, fdot2(x5, av5, 0.f)));
      z[k] = fmaf(1.5f, Tl, T);
    }
#pragma unroll
    for (int k = 0; k < 4; ++k) z[k] = dpp16_allsum(z[k]);
    float w[4];
#pragma unroll
    for (int k = 0; k < 4; ++k) {
      w[k] = fexp2(fminf(z[k] + prv, 80.f));
      den += w[k];
    }
#pragma unroll
    for (int k = 0; k < 4; ++k) {
      unsigned ux = s8[k].x, uy = s8[k].y, u5 = (unsigned)s1[k];
      FMAMIX_LO(acc[0], w[k], ux);
      FMAMIX_HI(acc[1], w[k], ux);
      FMAMIX_LO(acc[2], w[k], uy);
      FMAMIX_HI(acc[3], w[k], uy);
      FMAMIX_LO(acc[4], w[k], u5);
    }
#pragma unroll
    for (int k = 0; k < 4; ++k) { s8[k] = n8[k]; s1[k] = n1[k]; }
  }

#pragma unroll
  for (int k = 0; k < 3; ++k) {
    if (k < rem) {
      hf2 x01 = __builtin_bit_cast(hf2, s8[k].x);
      hf2 x23 = __builtin_bit_cast(hf2, s8[k].y);
      hf2 x5{__builtin_bit_cast(_Float16, s1[k]), (_Float16)0.f};
      float T = fdot2(habs2(x01 + xr01), av01,
                fdot2(habs2(x23 + xr23), av23,
                fdot2(habs2(x5 + xr5), av5, 0.f)));
      float Tl = fdot2(x01, av01, fdot2(x23, av23, fdot2(x5, av5, 0.f)));
      float z = fmaf(1.5f, Tl, T);
      z = dpp16_allsum(z);
      float w = fexp2(fminf(z + prv, 80.f));
      den += w;
      unsigned ux = s8[k].x, uy = s8[k].y, u5 = (unsigned)s1[k];
      FMAMIX_LO(acc[0], w, ux);
      FMAMIX_HI(acc[1], w, ux);
      FMAMIX_LO(acc[2], w, uy);
      FMAMIX_HI(acc[3], w, uy);
      FMAMIX_LO(acc[4], w, u5);
    }
  }

  float inv = 1.f / (den + 1e-16f);
  union { v2h h[2]; u16x4 o; } u;
  u.h[0] = pkrtz(fmaf(acc[0], inv, bp4.x), fmaf(acc[1], inv, bp4.y));
  u.h[1] = pkrtz(fmaf(acc[2], inv, bp4.z), fmaf(acc[3], inv, bp4.w));
  *(u16x4*)(out + (size_t)d * NPERM + lane * 4) = u.o;
  out[(size_t)d * NPERM + 256 + lane] = f2h(fmaf(acc[4], inv, bp5));
}

// ======================= BatchNorm reduce (pure atomicAdd; no fences) =============
__global__ __launch_bounds__(320) void k_bn_reduce(const ushort* __restrict__ h,
                                                   float* __restrict__ colsum,
                                                   float* __restrict__ colsq,
                                                   int n, int rows_per_block) {
  int c = threadIdx.x;
  int r0 = blockIdx.x * rows_per_block;
  int r1 = min(r0 + rows_per_block, n);
  float s = 0.f, s2 = 0.f;
  for (int r = r0; r < r1; ++r) {
    float v = h2f(h[(size_t)r * NPERM + c]);
    s += v;
    s2 += v * v;
  }
  atomicAdd(&colsum[c], s);
  atomicAdd(&colsq[c], s2);
}

// ======================= fused BN(coef inline) + leaky-relu + classifier ===========
__global__ __launch_bounds__(256) void k_bn_classifier(
    const ushort* __restrict__ h, const float* __restrict__ bnsum,
    const float* __restrict__ bnsq, const float* __restrict__ gp,
    const float* __restrict__ btp, float invN, const float* __restrict__ wc0,
    const float* __restrict__ wc1, const float* __restrict__ bc,
    float* __restrict__ out, int n) {
  int wave = threadIdx.x >> 6, lane = threadIdx.x & 63;
  int r = blockIdx.x * 4 + wave;
  if (r >= n) return;
  float a0 = 0.f, a1 = 0.f;
#pragma unroll
  for (int k = 0; k < SLOTS; ++k) {
    int slot = lane + 64 * k;
    float mu = bnsum[slot] * invN;
    float var = bnsq[slot] * invN - mu * mu;
    float sc = rsqrtf(var + BN_EPS) * gp[slot];
    float sh = btp[slot] - mu * sc;
    float v = fmaf(h2f(h[(size_t)r * NPERM + slot]), sc, sh);
    v = (v > 0.f) ? v : 0.01f * v;
    a0 = fmaf(v, wc0[slot], a0);
    a1 = fmaf(v, wc1[slot], a1);
  }
#pragma unroll
  for (int off = 32; off > 0; off >>= 1) {
    a0 += __shfl_xor(a0, off, 64);
    a1 += __shfl_xor(a1, off, 64);
  }
  if (lane == 0) {
    out[(size_t)2 * r] = a0 + bc[0];
    out[(size_t)2 * r + 1] = a1 + bc[1];
  }
}

// ======================= host launch =======================
extern "C" void kernel_launch(void* const* d_in, const int* in_sizes, int n_in,
                              void* d_out, int out_size, void* d_ws, size_t ws_size,
                              hipStream_t stream) {
  const float* x      = (const float*)d_in[0];
  const int*   eidx   = (const int*)d_in[1];
  const float* Wl1    = (const float*)d_in[2];
  const float* bl1    = (const float*)d_in[3];
  const float* Wr1    = (const float*)d_in[4];
  const float* br1    = (const float*)d_in[5];
  const float* att1   = (const float*)d_in[6];
  const float* b1     = (const float*)d_in[7];
  const float* Wl2    = (const float*)d_in[8];
  const float* bl2    = (const float*)d_in[9];
  const float* Wr2    = (const float*)d_in[10];
  const float* br2    = (const float*)d_in[11];
  const float* att2   = (const float*)d_in[12];
  const float* b2     = (const float*)d_in[13];
  const float* gamma  = (const float*)d_in[14];
  const float* beta   = (const float*)d_in[15];
  const float* Wc     = (const float*)d_in[16];
  const float* bc     = (const float*)d_in[17];
  float* out = (float*)d_out;

  const int FIN = 128;
  const int N = in_sizes[0] / FIN;   // 50000
  const int E = in_sizes[1] / 2;     // 800000

  const int* src = eidx;
  const int* dst = eidx + E;

  // ---- workspace layout ----
  ushort* h      = (ushort*)d_ws;                 // N*320 f16 permuted
  ushort* xl     = h + (size_t)N * NPERM;         // N*320
  ushort* xr     = xl + (size_t)N * NPERM;        // N*320
  ushort* wb1    = xr + (size_t)N * NPERM;        // 640*128 (L1 weights)
  ushort* wb2    = wb1 + (size_t)2 * NPERM * 128; // 640*320 (L2 weights)
  float* pb1     = (float*)(wb2 + (size_t)2 * NPERM * NPERM);  // 640
  float* pb2     = pb1 + 2 * NPERM;               // 640
  float* vecp    = pb2 + 2 * NPERM;               // 8*320
  int* row_ptr   = (int*)(vecp + 8 * NPERM);      // N+1
  int* cursor    = row_ptr + N + 1;               // N
  int* csr_src   = cursor + N;                    // E
  // ---- contiguous zero-init region (ONE memset) ----
  int* deg       = csr_src + E;                   // N
  unsigned* scanst = (unsigned*)(deg + N);        // 256 (lookback states)
  int* tickets   = (int*)(scanst + 256);          // 4 (unused; layout kept)
  float* colsum1 = (float*)(tickets + 4);         // 320
  float* colsq1  = colsum1 + NPERM;               // 320
  float* colsum2 = colsq1 + NPERM;                // 320
  float* colsq2  = colsum2 + NPERM;               // 320
  const size_t zero_bytes = (size_t)(N + 256 + 4 + 4 * NPERM) * 4;

  const int G = (N + 255) / 256;                  // scan blocks (196 < 256 CUs)
  const int AGGB = (N + 3) / 4;
  const int AGG2 = (N + 1) / 2;
  const int GEMMB = (N + 63) / 64;                // 64-row tiles
  const int FB = (E + 1023) / 1024;               // fill blocks (256 thr x 4 edges)
  const int HISTB = (E + 1279) / 1280;            // hist blocks (320 thr x 4 edges)

  const float* att1p = vecp;
  const float* b1p   = vecp + NPERM;
  const float* att2p = vecp + 2 * NPERM;
  const float* b2p   = vecp + 3 * NPERM;
  const float* gp    = vecp + 4 * NPERM;
  const float* btp   = vecp + 5 * NPERM;
  const float* wc0   = vecp + 6 * NPERM;
  const float* wc1   = vecp + 7 * NPERM;

  const int BNB = 1024;
  const int RPB = (N + BNB - 1) / BNB;
  const float invN = 1.f / (float)N;

  // 1: all zero-init in one memset
  hipMemsetAsync(deg, 0, zero_bytes, stream);
  // 2: weights L1+L2 + vecperm + histogram
  k_prep<<<5 * NPERM + HISTB, 320, 0, stream>>>(
      Wl1, bl1, Wr1, br1, Wl2, bl2, Wr2, br2, wb1, pb1, wb2, pb2,
      att1, b1, att2, b2, gamma, beta, Wc, vecp, dst, deg, E);
  // 3: single-pass scan -> row_ptr, cursor
  k_scan_lb<<<G, 256, 0, stream>>>(deg, scanst, row_ptr, cursor, N, E);
  // 4: GEMM layer1 + csr_fill (merged dispatch, independent work)
  k_gemm_a_lds<128, 0, 1, 64><<<GEMMB + FB, 256, 0, stream>>>(
      (const void*)x, wb1, pb1, nullptr, nullptr, nullptr, nullptr, 0.f,
      xl, xr, N, src, dst, cursor, csr_src, E, GEMMB);
  // 5: attention layer1
  k_agg<<<AGG2, 128, 0, stream>>>(xl, xr, csr_src, row_ptr, att1p, b1p, h, N);
  // 6: BN reduce layer1 (coef computed by consumer)
  k_bn_reduce<<<BNB, NPERM, 0, stream>>>(h, colsum1, colsq1, N, RPB);
  // 7: GEMM layer2 (BN coef + BN+leaky fused into A staging)
  k_gemm_a_lds<NPERM, 1, 0, 64><<<GEMMB, 256, 0, stream>>>(
      (const void*)h, wb2, pb2, colsum1, colsq1, gp, btp, invN,
      xl, xr, N, nullptr, nullptr, nullptr, nullptr, 0, GEMMB);
  // 8: attention layer2
  k_agg<<<AGG2, 128, 0, stream>>>(xl, xr, csr_src, row_ptr, att2p, b2p, h, N);
  // 9: BN reduce layer2
  k_bn_reduce<<<BNB, NPERM, 0, stream>>>(h, colsum2, colsq2, N, RPB);
  // 10: classifier (BN coef inline)
  k_bn_classifier<<<AGGB, 256, 0, stream>>>(h, colsum2, colsq2, gp, btp, invN,
                                            wc0, wc1, bc, out, N);
}